// Round 13
// baseline (2929.050 us; speedup 1.0000x reference)
//
#include <hip/hip_runtime.h>
#include <hip/hip_bf16.h>

typedef unsigned short u16;
typedef unsigned int u32;
typedef unsigned long long u64;
typedef __attribute__((ext_vector_type(8))) short short8;
typedef __attribute__((ext_vector_type(4))) unsigned int u32x4;
typedef __attribute__((ext_vector_type(4))) float f32x4;
typedef __attribute__((ext_vector_type(8))) _Float16 half8;

__device__ __forceinline__ u16 f2h(float f) {
  _Float16 h = (_Float16)f;
  u16 r;
  __builtin_memcpy(&r, &h, 2);
  return r;
}
__device__ __forceinline__ float h2f(u16 b) {
  _Float16 h;
  __builtin_memcpy(&h, &b, 2);
  return (float)h;
}
__device__ __forceinline__ half8 as_h8(short8 s) {
  half8 h;
  __builtin_memcpy(&h, &s, 16);
  return h;
}
__device__ __forceinline__ half8 as_h8u(u32x4 s) {
  half8 h;
  __builtin_memcpy(&h, &s, 16);
  return h;
}

// f32 -> f16 convert (4 elems/thread)
__global__ void cvt16(const float* __restrict__ in, u16* __restrict__ out, int n) {
  int i = (blockIdx.x * blockDim.x + threadIdx.x) * 4;
  if (i < n) {
    f32x4 v = *(const f32x4*)(in + i);
    out[i + 0] = f2h(v[0]);
    out[i + 1] = f2h(v[1]);
    out[i + 2] = f2h(v[2]);
    out[i + 3] = f2h(v[3]);
  }
}

// ---------------------------------------------------------------------------
// Tiled f16 MFMA GEMM:  C[M][N] = A[M][K] * B[N][K]^T + bias[N]
// BM=BN=128, BK=128, block=512. REMAP: store row m -> (m&1023)*32+(m>>10)
// ---------------------------------------------------------------------------
template <bool A_F32, bool OUT_F32, bool REMAP>
__global__ __launch_bounds__(512, 1) void gemm_kernel(
    const void* __restrict__ Ag, const u16* __restrict__ Bg,
    const float* __restrict__ bias, void* __restrict__ Cg,
    int M, int N, int K) {
  __shared__ __align__(16) u16 As[128 * 128];
  __shared__ __align__(16) u16 Bs[128 * 128];
  const int tid = threadIdx.x;
  const int lane = tid & 63, wave = tid >> 6;
  const int wm = wave & 1, wn = wave >> 1;
  const int m0 = blockIdx.x * 128, n0 = blockIdx.y * 128;

  f32x4 acc[4][2];
#pragma unroll
  for (int i = 0; i < 4; ++i) {
    acc[i][0] = (f32x4){0.f, 0.f, 0.f, 0.f};
    acc[i][1] = (f32x4){0.f, 0.f, 0.f, 0.f};
  }

  const int nk = K >> 7;
  for (int ks = 0; ks < nk; ++ks) {
    for (int i = tid; i < 128 * 16; i += 512) {
      int r = i >> 4, c = i & 15;
      int sw = c ^ (r & 7);
      short8 v;
      if (A_F32) {
        const float* ap = (const float*)Ag + (size_t)(m0 + r) * K + ks * 128 + c * 8;
#pragma unroll
        for (int e = 0; e < 8; ++e) v[e] = (short)f2h(ap[e]);
      } else {
        v = *(const short8*)((const u16*)Ag + (size_t)(m0 + r) * K + ks * 128 + c * 8);
      }
      *(short8*)(As + (r * 16 + sw) * 8) = v;
    }
    for (int i = tid; i < 128 * 16; i += 512) {
      int r = i >> 4, c = i & 15;
      int sw = c ^ (r & 7);
      *(short8*)(Bs + (r * 16 + sw) * 8) =
          *(const short8*)(Bg + (size_t)(n0 + r) * K + ks * 128 + c * 8);
    }
    __syncthreads();
#pragma unroll
    for (int kb = 0; kb < 4; ++kb) {
      const int cq = kb * 4 + (lane >> 4);
      short8 bfr[2];
#pragma unroll
      for (int j = 0; j < 2; ++j) {
        int rr = wn * 32 + j * 16 + (lane & 15);
        bfr[j] = *(const short8*)(Bs + (rr * 16 + (cq ^ (rr & 7))) * 8);
      }
#pragma unroll
      for (int i2 = 0; i2 < 4; ++i2) {
        int rr = wm * 64 + i2 * 16 + (lane & 15);
        short8 af = *(const short8*)(As + (rr * 16 + (cq ^ (rr & 7))) * 8);
        acc[i2][0] = __builtin_amdgcn_mfma_f32_16x16x32_f16(as_h8(af), as_h8(bfr[0]),
                                                            acc[i2][0], 0, 0, 0);
        acc[i2][1] = __builtin_amdgcn_mfma_f32_16x16x32_f16(as_h8(af), as_h8(bfr[1]),
                                                            acc[i2][1], 0, 0, 0);
      }
    }
    __syncthreads();
  }
#pragma unroll
  for (int i2 = 0; i2 < 4; ++i2) {
#pragma unroll
    for (int j = 0; j < 2; ++j) {
      int ncol = n0 + wn * 32 + j * 16 + (lane & 15);
      float bv = bias[ncol];
#pragma unroll
      for (int r2 = 0; r2 < 4; ++r2) {
        int mrow = m0 + wm * 64 + i2 * 16 + ((lane >> 4) << 2) + r2;
        size_t orow = REMAP ? ((size_t)(mrow & 1023) * 32 + (mrow >> 10)) : (size_t)mrow;
        float v = acc[i2][j][r2] + bv;
        if (OUT_F32)
          ((float*)Cg)[orow * N + ncol] = v;
        else
          ((u16*)Cg)[orow * N + ncol] = f2h(v);
      }
    }
  }
}

// ---------------------------------------------------------------------------
// Persistent GRU recurrence: 64 fully-AUTONOMOUS waves (64 WGs x 64 thr).
// Sync protocol IDENTICAL to proven R6/R11 (tag-validate-retry on sc0 sc1 LLC
// exchange, 2-bit step tags in f16 bit0, fire-and-forget stores).
// Placement-only change vs R11: the probe batch for step t+1 is issued
// SPECULATIVELY at the end of step t (right after this wave's tagged stores),
// so the first LLC sample is in flight during gates; validation at step t+1
// entry then frequently accepts the first sample, saving one retry RT.
// Retry loop body (wait -> validate -> reissue) is byte-identical to R11.
// ---------------------------------------------------------------------------
#define TS 1024

__global__ __launch_bounds__(64, 1) void gru_kernel(
    const float* __restrict__ w_hh, const float* __restrict__ b_hh,
    const u16* __restrict__ wx, u16* __restrict__ hs,
    u16* __restrict__ hbuf) {
  const int lane = threadIdx.x & 63;
  const int wgq = blockIdx.x >> 2;        // h-col quad 0..15 (K-block kb)
  const int mt = (blockIdx.x >> 1) & 1;   // seq half
  const int jblk = blockIdx.x & 1;        // 16-col half within the quad
  const int colL = jblk * 16 + (lane & 15);  // col local 0..31
  const int colH = wgq * 32 + colL;          // global h col
  const int k0 = (lane >> 4) << 3;
  const int seqb = mt * 16 + ((lane >> 4) << 2);  // base seq for r=0

  // ---- weights f16, register-resident: 3 gates x 16 k-blocks
  half8 wf[3][16];
#pragma unroll
  for (int g = 0; g < 3; ++g) {
    const float* wrow = w_hh + (size_t)(g * 512 + colH) * 512 + k0;
#pragma unroll
    for (int kb = 0; kb < 16; ++kb) {
      half8 v;
#pragma unroll
      for (int e = 0; e < 8; ++e) v[e] = (_Float16)wrow[kb * 32 + e];
      wf[g][kb] = v;
    }
  }
  const float bR = b_hh[colH], bZ = b_hh[512 + colH], bN = b_hh[1024 + colH];

  // probe voffsets (bytes): consumer A-frag dwordx4 at ((kb*2+mt)*64+lane)*16
  u32 pvoff[16];
#pragma unroll
  for (int kb = 0; kb < 16; ++kb) pvoff[kb] = (u32)(((kb * 2 + mt) * 64 + lane) * 16);
  // store voffset (bytes) for r=0; r adds 16B (lane_c increments by 1)
  const u32 svoff0 =
      (u32)((((wgq * 2 + mt) * 64 +
              (((lane >> 4) << 2) | (((colL >> 3) & 3) << 4))) * 8 + (lane & 7)) * 2);

  // wx(0) prefetch (12 u16 per lane)
  u16 wxr[3][4];
#pragma unroll
  for (int g = 0; g < 3; ++g)
#pragma unroll
    for (int r = 0; r < 4; ++r)
      wxr[g][r] = wx[(size_t)(seqb + r) * 1536 + g * 512 + colH];

  float h_old[4] = {0.f, 0.f, 0.f, 0.f};
  u32x4 f[16];           // loop-carried speculative probe batch
  int budget = 1000000;  // bounded-retry guard (fast-fail, never hang)

  for (int t = 0; t < TS; ++t) {
    f32x4 accS[3];
    u16 wxn[3][4];
    if (t > 0) {
      const u64 sb = (u64)(hbuf + ((t - 1) & 1) * 16384);
      const u32 p = (u32)((t - 1) & 1) | ((u32)(((t - 1) >> 1) & 1) << 16);
      // speculative batch already in flight (issued at end of step t-1).
      // wait -> validate -> reissue loop (identical protocol to R11)
      for (;;) {
        asm volatile("s_waitcnt vmcnt(0)" ::: "memory");
        __builtin_amdgcn_sched_barrier(0);
        u32 aOR = 0u, aAND = 0xFFFFFFFFu;
#pragma unroll
        for (int kb = 0; kb < 16; ++kb)
#pragma unroll
          for (int d = 0; d < 4; ++d) { aOR |= f[kb][d]; aAND &= f[kb][d]; }
        int ok = ((aOR & 0x00010001u) == p) & ((aAND & 0x00010001u) == p);
        if (__all(ok)) break;
        if (--budget < 0) break;  // diagnosable fast-fail, no timeout
#pragma unroll
        for (int kb = 0; kb < 16; ++kb)
          asm volatile("global_load_dwordx4 %0, %1, %2 sc0 sc1"
                       : "=v"(f[kb]) : "v"(pvoff[kb]), "s"(sb) : "memory");
      }
      // ---- EARLY hs write of h(t-1) from registers (bit-identical to the
      //      values exchanged last step); HBM ack hides under MFMA+gates
#pragma unroll
      for (int r = 0; r < 4; ++r)
        hs[((size_t)((seqb + r) * TS + (t - 1)) << 9) + colH] = f2h(h_old[r]);
      // ---- wx(t+1) prefetch issued before MFMA (completion off critical path)
      {
        int tp = (t + 1 < TS) ? t + 1 : t;
#pragma unroll
        for (int g = 0; g < 3; ++g)
#pragma unroll
          for (int r = 0; r < 4; ++r)
            wxn[g][r] = wx[(size_t)(tp * 32 + seqb + r) * 1536 + g * 512 + colH];
      }
      f32x4 a[3][2];
#pragma unroll
      for (int g = 0; g < 3; ++g) {
        a[g][0] = (f32x4){0.f, 0.f, 0.f, 0.f};
        a[g][1] = (f32x4){0.f, 0.f, 0.f, 0.f};
      }
#pragma unroll
      for (int kb = 0; kb < 16; kb += 2) {
        half8 h0 = as_h8u(f[kb]), h1 = as_h8u(f[kb + 1]);
#pragma unroll
        for (int g = 0; g < 3; ++g) {
          a[g][0] = __builtin_amdgcn_mfma_f32_16x16x32_f16(h0, wf[g][kb], a[g][0], 0, 0, 0);
          a[g][1] = __builtin_amdgcn_mfma_f32_16x16x32_f16(h1, wf[g][kb + 1], a[g][1], 0, 0, 0);
        }
      }
#pragma unroll
      for (int g = 0; g < 3; ++g) accS[g] = a[g][0] + a[g][1];
    } else {
#pragma unroll
      for (int g = 0; g < 3; ++g) accS[g] = (f32x4){0.f, 0.f, 0.f, 0.f};
#pragma unroll
      for (int g = 0; g < 3; ++g)
#pragma unroll
        for (int r = 0; r < 4; ++r)
          wxn[g][r] = wx[(size_t)(1 * 32 + seqb + r) * 1536 + g * 512 + colH];
    }

    // gates in registers; tagged h store issues per-r ASAP
    const u64 sb2 = (u64)(hbuf + (t & 1) * 16384);
    const u32 tagbit = (colL & 1) ? (u32)((t >> 1) & 1) : (u32)(t & 1);
#pragma unroll
    for (int r = 0; r < 4; ++r) {
      float pr = h2f(wxr[0][r]) + accS[0][r] + bR;
      float pz = h2f(wxr[1][r]) + accS[1][r] + bZ;
      float rr = __builtin_amdgcn_rcpf(1.f + __expf(-pr));
      float zz = __builtin_amdgcn_rcpf(1.f + __expf(-pz));
      float xx = h2f(wxr[2][r]) + rr * (accS[2][r] + bN);
      float nn = 1.f - 2.f * __builtin_amdgcn_rcpf(__expf(2.f * xx) + 1.f);
      float hv = (1.f - zz) * nn + zz * h_old[r];
      h_old[r] = hv;
      u32 hbits = (u32)f2h(hv);
      u32 tv = (hbits & 0xFFFEu) | tagbit;
      asm volatile("global_store_short %0, %1, %2 sc0 sc1"
                   :: "v"(svoff0 + r * 16), "v"(tv), "s"(sb2) : "memory");
      if (t == TS - 1)  // final step: no step t+1 exists to write hs[1023]
        hs[((size_t)((seqb + r) * TS + t) << 9) + colH] = (u16)hbits;
    }
    // ---- speculative probe issue for step t+1 (slot t&1, tag t&3):
    //      first LLC sample flies during the next step's entry; if it misses
    //      partners' stores (or our own), tags mismatch and the normal retry
    //      loop re-issues. Protocol unchanged.
    if (t + 1 < TS) {
      const u64 sbn = (u64)(hbuf + (t & 1) * 16384);
#pragma unroll
      for (int kb = 0; kb < 16; ++kb)
        asm volatile("global_load_dwordx4 %0, %1, %2 sc0 sc1"
                     : "=v"(f[kb]) : "v"(pvoff[kb]), "s"(sbn) : "memory");
    }
#pragma unroll
    for (int g = 0; g < 3; ++g)
#pragma unroll
      for (int r = 0; r < 4; ++r) wxr[g][r] = wxn[g][r];
  }
}

// ---------------------------------------------------------------------------
extern "C" void kernel_launch(void* const* d_in, const int* in_sizes, int n_in,
                              void* d_out, int out_size, void* d_ws, size_t ws_size,
                              hipStream_t stream) {
  const float* src = (const float*)d_in[0];   // [32,1024,256]
  const float* w_ih = (const float*)d_in[1];  // [1536,256]
  const float* w_hh = (const float*)d_in[2];  // [1536,512]
  const float* b_ih = (const float*)d_in[3];  // [1536]
  const float* b_hh = (const float*)d_in[4];  // [1536]
  const float* regw = (const float*)d_in[5];  // [256,512]
  const float* regb = (const float*)d_in[6];  // [256]

  char* ws = (char*)d_ws;
  u16* wx = (u16*)(ws);                  // [t][seq][1536] f16 = 100663296 B
  u16* hs = (u16*)(ws + 100663296LL);    // [seq*1024+t][512] f16 = 33554432 B
  u16* wihb = (u16*)(ws + 134217728LL);  // 1536x256 f16 (dead after wx GEMM)
  u16* rwb = (u16*)(ws + 135004160LL);   // 256x512 f16
  // hbuf reuses the dead wihb region during gru:
  u16* hbuf = (u16*)(ws + 134217728LL + 4096);  // 2 x 32 KB frag double-buffer

  cvt16<<<384, 256, 0, stream>>>(w_ih, wihb, 393216);
  cvt16<<<128, 256, 0, stream>>>(regw, rwb, 131072);

  {  // wx = src @ w_ih^T + b_ih, stored remapped [t][seq][1536] (f16)
    dim3 g(256, 12);
    gemm_kernel<true, false, true><<<g, 512, 0, stream>>>(
        (const void*)src, wihb, b_ih, (void*)wx, 32768, 1536, 256);
  }
  // init hbuf to 0xFF AFTER the wx GEMM consumed wihb: tag bits (1,1) mismatch
  // t=1/t=2 expectations; also kills the 0xAA-poison (tag 0) collision.
  hipMemsetAsync(ws + 134217728LL + 4096, 0xFF, 65536, stream);
  gru_kernel<<<64, 64, 0, stream>>>(w_hh, b_hh, wx, hs, hbuf);
  {  // out = hs @ reg_w^T + reg_b  (f32 out)
    dim3 g(256, 2);
    gemm_kernel<false, true, false><<<g, 512, 0, stream>>>(
        (const void*)hs, rwb, regb, d_out, 32768, 256, 512);
  }
}

// Round 14
// 2165.278 us; speedup vs baseline: 1.3527x; 1.3527x over previous
//
#include <hip/hip_runtime.h>
#include <hip/hip_bf16.h>

typedef unsigned short u16;
typedef unsigned int u32;
typedef unsigned long long u64;
typedef __attribute__((ext_vector_type(8))) short short8;
typedef __attribute__((ext_vector_type(4))) unsigned int u32x4;
typedef __attribute__((ext_vector_type(4))) float f32x4;
typedef __attribute__((ext_vector_type(8))) _Float16 half8;

__device__ __forceinline__ u16 f2h(float f) {
  _Float16 h = (_Float16)f;
  u16 r;
  __builtin_memcpy(&r, &h, 2);
  return r;
}
__device__ __forceinline__ float h2f(u16 b) {
  _Float16 h;
  __builtin_memcpy(&h, &b, 2);
  return (float)h;
}
__device__ __forceinline__ half8 as_h8(short8 s) {
  half8 h;
  __builtin_memcpy(&h, &s, 16);
  return h;
}
__device__ __forceinline__ half8 as_h8u(u32x4 s) {
  half8 h;
  __builtin_memcpy(&h, &s, 16);
  return h;
}

// f32 -> f16 convert (4 elems/thread)
__global__ void cvt16(const float* __restrict__ in, u16* __restrict__ out, int n) {
  int i = (blockIdx.x * blockDim.x + threadIdx.x) * 4;
  if (i < n) {
    f32x4 v = *(const f32x4*)(in + i);
    out[i + 0] = f2h(v[0]);
    out[i + 1] = f2h(v[1]);
    out[i + 2] = f2h(v[2]);
    out[i + 3] = f2h(v[3]);
  }
}

// ---------------------------------------------------------------------------
// Tiled f16 MFMA GEMM:  C[M][N] = A[M][K] * B[N][K]^T + bias[N]
// BM=BN=128, BK=128, block=512. REMAP: store row m -> (m&1023)*32+(m>>10)
// ---------------------------------------------------------------------------
template <bool A_F32, bool OUT_F32, bool REMAP>
__global__ __launch_bounds__(512, 1) void gemm_kernel(
    const void* __restrict__ Ag, const u16* __restrict__ Bg,
    const float* __restrict__ bias, void* __restrict__ Cg,
    int M, int N, int K) {
  __shared__ __align__(16) u16 As[128 * 128];
  __shared__ __align__(16) u16 Bs[128 * 128];
  const int tid = threadIdx.x;
  const int lane = tid & 63, wave = tid >> 6;
  const int wm = wave & 1, wn = wave >> 1;
  const int m0 = blockIdx.x * 128, n0 = blockIdx.y * 128;

  f32x4 acc[4][2];
#pragma unroll
  for (int i = 0; i < 4; ++i) {
    acc[i][0] = (f32x4){0.f, 0.f, 0.f, 0.f};
    acc[i][1] = (f32x4){0.f, 0.f, 0.f, 0.f};
  }

  const int nk = K >> 7;
  for (int ks = 0; ks < nk; ++ks) {
    for (int i = tid; i < 128 * 16; i += 512) {
      int r = i >> 4, c = i & 15;
      int sw = c ^ (r & 7);
      short8 v;
      if (A_F32) {
        const float* ap = (const float*)Ag + (size_t)(m0 + r) * K + ks * 128 + c * 8;
#pragma unroll
        for (int e = 0; e < 8; ++e) v[e] = (short)f2h(ap[e]);
      } else {
        v = *(const short8*)((const u16*)Ag + (size_t)(m0 + r) * K + ks * 128 + c * 8);
      }
      *(short8*)(As + (r * 16 + sw) * 8) = v;
    }
    for (int i = tid; i < 128 * 16; i += 512) {
      int r = i >> 4, c = i & 15;
      int sw = c ^ (r & 7);
      *(short8*)(Bs + (r * 16 + sw) * 8) =
          *(const short8*)(Bg + (size_t)(n0 + r) * K + ks * 128 + c * 8);
    }
    __syncthreads();
#pragma unroll
    for (int kb = 0; kb < 4; ++kb) {
      const int cq = kb * 4 + (lane >> 4);
      short8 bfr[2];
#pragma unroll
      for (int j = 0; j < 2; ++j) {
        int rr = wn * 32 + j * 16 + (lane & 15);
        bfr[j] = *(const short8*)(Bs + (rr * 16 + (cq ^ (rr & 7))) * 8);
      }
#pragma unroll
      for (int i2 = 0; i2 < 4; ++i2) {
        int rr = wm * 64 + i2 * 16 + (lane & 15);
        short8 af = *(const short8*)(As + (rr * 16 + (cq ^ (rr & 7))) * 8);
        acc[i2][0] = __builtin_amdgcn_mfma_f32_16x16x32_f16(as_h8(af), as_h8(bfr[0]),
                                                            acc[i2][0], 0, 0, 0);
        acc[i2][1] = __builtin_amdgcn_mfma_f32_16x16x32_f16(as_h8(af), as_h8(bfr[1]),
                                                            acc[i2][1], 0, 0, 0);
      }
    }
    __syncthreads();
  }
#pragma unroll
  for (int i2 = 0; i2 < 4; ++i2) {
#pragma unroll
    for (int j = 0; j < 2; ++j) {
      int ncol = n0 + wn * 32 + j * 16 + (lane & 15);
      float bv = bias[ncol];
#pragma unroll
      for (int r2 = 0; r2 < 4; ++r2) {
        int mrow = m0 + wm * 64 + i2 * 16 + ((lane >> 4) << 2) + r2;
        size_t orow = REMAP ? ((size_t)(mrow & 1023) * 32 + (mrow >> 10)) : (size_t)mrow;
        float v = acc[i2][j][r2] + bv;
        if (OUT_F32)
          ((float*)Cg)[orow * N + ncol] = v;
        else
          ((u16*)Cg)[orow * N + ncol] = f2h(v);
      }
    }
  }
}

// ---------------------------------------------------------------------------
// Persistent GRU recurrence: 64 fully-AUTONOMOUS waves (64 WGs x 64 thr).
// Sync protocol IDENTICAL to proven R6/R11 (tag-validate-retry on sc0 sc1 LLC
// exchange, 2-bit step tags in f16 bit0, fire-and-forget stores).
// Timing-only changes vs R11 (retry loop byte-identical):
//  - early-hs stores + wx prefetch issued BEFORE the probe loop (independent
//    of validated data; removes their issue time from the post-validation
//    path and naturally delays the first probe sample)
//  - one s_sleep before the probe loop so the first LLC sample lands after
//    partners' store visibility -> converts ~2 probe rounds to ~1
// ---------------------------------------------------------------------------
#define TS 1024

__global__ __launch_bounds__(64, 1) void gru_kernel(
    const float* __restrict__ w_hh, const float* __restrict__ b_hh,
    const u16* __restrict__ wx, u16* __restrict__ hs,
    u16* __restrict__ hbuf) {
  const int lane = threadIdx.x & 63;
  const int wgq = blockIdx.x >> 2;        // h-col quad 0..15 (K-block kb)
  const int mt = (blockIdx.x >> 1) & 1;   // seq half
  const int jblk = blockIdx.x & 1;        // 16-col half within the quad
  const int colL = jblk * 16 + (lane & 15);  // col local 0..31
  const int colH = wgq * 32 + colL;          // global h col
  const int k0 = (lane >> 4) << 3;
  const int seqb = mt * 16 + ((lane >> 4) << 2);  // base seq for r=0

  // ---- weights f16, register-resident: 3 gates x 16 k-blocks
  half8 wf[3][16];
#pragma unroll
  for (int g = 0; g < 3; ++g) {
    const float* wrow = w_hh + (size_t)(g * 512 + colH) * 512 + k0;
#pragma unroll
    for (int kb = 0; kb < 16; ++kb) {
      half8 v;
#pragma unroll
      for (int e = 0; e < 8; ++e) v[e] = (_Float16)wrow[kb * 32 + e];
      wf[g][kb] = v;
    }
  }
  const float bR = b_hh[colH], bZ = b_hh[512 + colH], bN = b_hh[1024 + colH];

  // probe voffsets (bytes): consumer A-frag dwordx4 at ((kb*2+mt)*64+lane)*16
  u32 pvoff[16];
#pragma unroll
  for (int kb = 0; kb < 16; ++kb) pvoff[kb] = (u32)(((kb * 2 + mt) * 64 + lane) * 16);
  // store voffset (bytes) for r=0; r adds 16B (lane_c increments by 1)
  const u32 svoff0 =
      (u32)((((wgq * 2 + mt) * 64 +
              (((lane >> 4) << 2) | (((colL >> 3) & 3) << 4))) * 8 + (lane & 7)) * 2);

  // wx(0) prefetch (12 u16 per lane)
  u16 wxr[3][4];
#pragma unroll
  for (int g = 0; g < 3; ++g)
#pragma unroll
    for (int r = 0; r < 4; ++r)
      wxr[g][r] = wx[(size_t)(seqb + r) * 1536 + g * 512 + colH];

  float h_old[4] = {0.f, 0.f, 0.f, 0.f};
  int budget = 4000000;  // bounded-retry guard (fast-fail, never hang)

  for (int t = 0; t < TS; ++t) {
    f32x4 accS[3];
    u16 wxn[3][4];
    if (t > 0) {
      // ---- EARLY hs write of h(t-1) from registers (independent of this
      //      step's validation; ack hides under the probe RT)
#pragma unroll
      for (int r = 0; r < 4; ++r)
        hs[((size_t)((seqb + r) * TS + (t - 1)) << 9) + colH] = f2h(h_old[r]);
      // ---- wx(t+1) prefetch issued before the probe loop
      {
        int tp = (t + 1 < TS) ? t + 1 : t;
#pragma unroll
        for (int g = 0; g < 3; ++g)
#pragma unroll
          for (int r = 0; r < 4; ++r)
            wxn[g][r] = wx[(size_t)(tp * 32 + seqb + r) * 1536 + g * 512 + colH];
      }
      // ---- short sleep so the first probe samples the LLC after partners'
      //      store visibility (timing-only; protocol unchanged)
      __builtin_amdgcn_s_sleep(8);

      const u64 sb = (u64)(hbuf + ((t - 1) & 1) * 16384);
      const u32 p = (u32)((t - 1) & 1) | ((u32)(((t - 1) >> 1) & 1) << 16);
      u32x4 f[16];
      // validate-retry: data is fresh iff every dword carries tag (t-1)&3
      for (;;) {
#pragma unroll
        for (int kb = 0; kb < 16; ++kb)
          asm volatile("global_load_dwordx4 %0, %1, %2 sc0 sc1"
                       : "=v"(f[kb]) : "v"(pvoff[kb]), "s"(sb) : "memory");
        asm volatile("s_waitcnt vmcnt(0)" ::: "memory");
        __builtin_amdgcn_sched_barrier(0);
        u32 aOR = 0u, aAND = 0xFFFFFFFFu;
#pragma unroll
        for (int kb = 0; kb < 16; ++kb)
#pragma unroll
          for (int d = 0; d < 4; ++d) { aOR |= f[kb][d]; aAND &= f[kb][d]; }
        int ok = ((aOR & 0x00010001u) == p) & ((aAND & 0x00010001u) == p);
        if (__all(ok)) break;
        if (--budget < 0) break;  // diagnosable fast-fail, no timeout
      }
      f32x4 a[3][2];
#pragma unroll
      for (int g = 0; g < 3; ++g) {
        a[g][0] = (f32x4){0.f, 0.f, 0.f, 0.f};
        a[g][1] = (f32x4){0.f, 0.f, 0.f, 0.f};
      }
#pragma unroll
      for (int kb = 0; kb < 16; kb += 2) {
        half8 h0 = as_h8u(f[kb]), h1 = as_h8u(f[kb + 1]);
#pragma unroll
        for (int g = 0; g < 3; ++g) {
          a[g][0] = __builtin_amdgcn_mfma_f32_16x16x32_f16(h0, wf[g][kb], a[g][0], 0, 0, 0);
          a[g][1] = __builtin_amdgcn_mfma_f32_16x16x32_f16(h1, wf[g][kb + 1], a[g][1], 0, 0, 0);
        }
      }
#pragma unroll
      for (int g = 0; g < 3; ++g) accS[g] = a[g][0] + a[g][1];
    } else {
#pragma unroll
      for (int g = 0; g < 3; ++g) accS[g] = (f32x4){0.f, 0.f, 0.f, 0.f};
#pragma unroll
      for (int g = 0; g < 3; ++g)
#pragma unroll
        for (int r = 0; r < 4; ++r)
          wxn[g][r] = wx[(size_t)(1 * 32 + seqb + r) * 1536 + g * 512 + colH];
    }

    // gates in registers; tagged h store issues per-r ASAP
    const u64 sb2 = (u64)(hbuf + (t & 1) * 16384);
    const u32 tagbit = (colL & 1) ? (u32)((t >> 1) & 1) : (u32)(t & 1);
#pragma unroll
    for (int r = 0; r < 4; ++r) {
      float pr = h2f(wxr[0][r]) + accS[0][r] + bR;
      float pz = h2f(wxr[1][r]) + accS[1][r] + bZ;
      float rr = __builtin_amdgcn_rcpf(1.f + __expf(-pr));
      float zz = __builtin_amdgcn_rcpf(1.f + __expf(-pz));
      float xx = h2f(wxr[2][r]) + rr * (accS[2][r] + bN);
      float nn = 1.f - 2.f * __builtin_amdgcn_rcpf(__expf(2.f * xx) + 1.f);
      float hv = (1.f - zz) * nn + zz * h_old[r];
      h_old[r] = hv;
      u32 hbits = (u32)f2h(hv);
      u32 tv = (hbits & 0xFFFEu) | tagbit;
      asm volatile("global_store_short %0, %1, %2 sc0 sc1"
                   :: "v"(svoff0 + r * 16), "v"(tv), "s"(sb2) : "memory");
      if (t == TS - 1)  // final step: no step t+1 exists to write hs[1023]
        hs[((size_t)((seqb + r) * TS + t) << 9) + colH] = (u16)hbits;
    }
#pragma unroll
    for (int g = 0; g < 3; ++g)
#pragma unroll
      for (int r = 0; r < 4; ++r) wxr[g][r] = wxn[g][r];
  }
}

// ---------------------------------------------------------------------------
extern "C" void kernel_launch(void* const* d_in, const int* in_sizes, int n_in,
                              void* d_out, int out_size, void* d_ws, size_t ws_size,
                              hipStream_t stream) {
  const float* src = (const float*)d_in[0];   // [32,1024,256]
  const float* w_ih = (const float*)d_in[1];  // [1536,256]
  const float* w_hh = (const float*)d_in[2];  // [1536,512]
  const float* b_ih = (const float*)d_in[3];  // [1536]
  const float* b_hh = (const float*)d_in[4];  // [1536]
  const float* regw = (const float*)d_in[5];  // [256,512]
  const float* regb = (const float*)d_in[6];  // [256]

  char* ws = (char*)d_ws;
  u16* wx = (u16*)(ws);                  // [t][seq][1536] f16 = 100663296 B
  u16* hs = (u16*)(ws + 100663296LL);    // [seq*1024+t][512] f16 = 33554432 B
  u16* wihb = (u16*)(ws + 134217728LL);  // 1536x256 f16 (dead after wx GEMM)
  u16* rwb = (u16*)(ws + 135004160LL);   // 256x512 f16
  // hbuf reuses the dead wihb region during gru:
  u16* hbuf = (u16*)(ws + 134217728LL + 4096);  // 2 x 32 KB frag double-buffer

  cvt16<<<384, 256, 0, stream>>>(w_ih, wihb, 393216);
  cvt16<<<128, 256, 0, stream>>>(regw, rwb, 131072);

  {  // wx = src @ w_ih^T + b_ih, stored remapped [t][seq][1536] (f16)
    dim3 g(256, 12);
    gemm_kernel<true, false, true><<<g, 512, 0, stream>>>(
        (const void*)src, wihb, b_ih, (void*)wx, 32768, 1536, 256);
  }
  // init hbuf to 0xFF AFTER the wx GEMM consumed wihb: tag bits (1,1) mismatch
  // t=1/t=2 expectations; also kills the 0xAA-poison (tag 0) collision.
  hipMemsetAsync(ws + 134217728LL + 4096, 0xFF, 65536, stream);
  gru_kernel<<<64, 64, 0, stream>>>(w_hh, b_hh, wx, hs, hbuf);
  {  // out = hs @ reg_w^T + reg_b  (f32 out)
    dim3 g(256, 2);
    gemm_kernel<false, true, false><<<g, 512, 0, stream>>>(
        (const void*)hs, rwb, regb, d_out, 32768, 256, 512);
  }
}